// Round 1
// baseline (39645.709 us; speedup 1.0000x reference)
//
#include <hip/hip_runtime.h>

// TrajectoryPredictor: 2-layer LSTM encoder (S=100) + 30-step autoregressive decoder.
// B=8192, I=15, H=128, O=2, F=30. fp32 throughout (CDNA4 has no fp32 MFMA; this
// round targets the 157 TF vector roofline ~2.8ms; bf16-MFMA is the next ladder).
//
// Parallelization: batch is embarrassingly parallel across the recurrence.
// 256 blocks x 512 threads; each block runs all 130 steps for 32 batch elements.
// Thread (j = tid&127, bg = tid>>7) computes all 4 gates of hidden unit j for
// 8 batch elements (acc[4][8], c-state in registers). h0/h1 double-buffered in
// LDS; weights pre-transposed to [m][j][gate] in d_ws for coalesced dwordx4.

#define BT   32
#define SEQ  100
#define NIN  15
#define FUT  30
#define TOT  (SEQ + FUT)

__device__ __forceinline__ float sigmoid_f(float v) {
  return 1.0f / (1.0f + __expf(-v));
}
__device__ __forceinline__ float tanh_f(float v) {
  float a = fabsf(v);
  float e = __expf(-2.0f * a);          // in (0,1], no overflow
  float t = (1.0f - e) / (1.0f + e);
  return (v < 0.0f) ? -t : t;
}

// ---- weight re-layout into workspace (runs every launch; ~820KB) ----
// ws float layout:
//   [0,      65536)  WT_HH0[m*512 + j*4 + g] = w_hh0[(g*128+j)*128 + m]
//   [65536, 131072)  WT_IH1  (same transform of w_ih1)
//   [131072,196608)  WT_HH1
//   [196608,204800)  WT_IH0[m*512 + j*4 + g], m in 0..15 (m=15 zero pad)
//   [204800,205312)  BV0[j*4+g] = b_ih0[g*128+j] + b_hh0[g*128+j]
//   [205312,205824)  BV1 likewise
__global__ void prep_kernel(const float* __restrict__ w_ih0, const float* __restrict__ w_hh0,
                            const float* __restrict__ b_ih0, const float* __restrict__ b_hh0,
                            const float* __restrict__ w_ih1, const float* __restrict__ w_hh1,
                            const float* __restrict__ b_ih1, const float* __restrict__ b_hh1,
                            float* __restrict__ ws)
{
  int idx = blockIdx.x * blockDim.x + threadIdx.x;
  if (idx < 196608) {
    int seg = idx >> 16;
    int r   = idx & 65535;
    int m   = r >> 9;
    int jg  = r & 511;
    int k   = (jg & 3) * 128 + (jg >> 2);    // gate-major row index
    const float* src = (seg == 0) ? w_hh0 : ((seg == 1) ? w_ih1 : w_hh1);
    ws[idx] = src[k * 128 + m];
  } else if (idx < 204800) {
    int r  = idx - 196608;
    int m  = r >> 9;
    int jg = r & 511;
    int k  = (jg & 3) * 128 + (jg >> 2);
    ws[idx] = (m < NIN) ? w_ih0[k * NIN + m] : 0.0f;
  } else if (idx < 205824) {
    int r     = idx - 204800;
    int which = r >> 9;
    int jg    = r & 511;
    int k     = (jg & 3) * 128 + (jg >> 2);
    ws[idx] = (which == 0) ? (b_ih0[k] + b_hh0[k]) : (b_ih1[k] + b_hh1[k]);
  }
}

// acc[g][q] += W[m][j][g] * H[b0+q][m], accumulated over m
#define MM_STEP(WPTR, HPTR, LDH, MLEN)                                         \
  for (int m = 0; m < (MLEN); m += 4) {                                        \
    float4 hv[8];                                                              \
    _Pragma("unroll")                                                          \
    for (int q = 0; q < 8; ++q)                                                \
      hv[q] = *(const float4*)&(HPTR)[(bl + q) * (LDH) + m];                   \
    _Pragma("unroll")                                                          \
    for (int mm = 0; mm < 4; ++mm) {                                           \
      float4 wv = *(const float4*)&(WPTR)[(m + mm) * 512 + j * 4];             \
      _Pragma("unroll")                                                        \
      for (int q = 0; q < 8; ++q) {                                            \
        float hvv = (mm == 0) ? hv[q].x : (mm == 1) ? hv[q].y                  \
                  : (mm == 2) ? hv[q].z : hv[q].w;                             \
        acc[0][q] = fmaf(wv.x, hvv, acc[0][q]);                                \
        acc[1][q] = fmaf(wv.y, hvv, acc[1][q]);                                \
        acc[2][q] = fmaf(wv.z, hvv, acc[2][q]);                                \
        acc[3][q] = fmaf(wv.w, hvv, acc[3][q]);                                \
      }                                                                        \
    }                                                                          \
  }

__global__ __launch_bounds__(512, 2)
void lstm_kernel(const float* __restrict__ x,
                 const float* __restrict__ ws,
                 const float* __restrict__ fcw,
                 const float* __restrict__ fcb,
                 float* __restrict__ out)
{
  __shared__ __align__(16) float sh0[2][BT][128];
  __shared__ __align__(16) float sh1[2][BT][128];
  __shared__ __align__(16) float sinp[BT][16];

  const float* WT_HH0 = ws;
  const float* WT_IH1 = ws + 65536;
  const float* WT_HH1 = ws + 131072;
  const float* WT_IH0 = ws + 196608;
  const float* BV0    = ws + 204800;
  const float* BV1    = ws + 205312;

  const int tid   = threadIdx.x;
  const int j     = tid & 127;    // hidden unit owned by this thread
  const int bg    = tid >> 7;     // batch group 0..3 (wave-uniform)
  const int bl    = bg * 8;       // local batch base (8 elems per thread)
  const int bbase = blockIdx.x * BT;

  float c0r[8], c1r[8];
  #pragma unroll
  for (int q = 0; q < 8; ++q) { c0r[q] = 0.0f; c1r[q] = 0.0f; }

  for (int t = tid; t < BT * 128; t += 512) {
    sh0[0][t >> 7][t & 127] = 0.0f;
    sh1[0][t >> 7][t & 127] = 0.0f;
  }
  if (tid < BT) sinp[tid][15] = 0.0f;            // zero pad column, never touched again
  if (tid < BT * NIN) {
    int b = tid / NIN, i = tid - b * NIN;
    sinp[b][i] = x[(bbase + b) * SEQ * NIN + i]; // x[:, 0, :]
  }

  const float4 bias0 = *(const float4*)(BV0 + j * 4);
  const float4 bias1 = *(const float4*)(BV1 + j * 4);

  __syncthreads();

  int cur = 0;
  for (int s = 0; s < TOT; ++s) {
    const int nxt = cur ^ 1;

    // ---------------- layer 0 ----------------
    float acc[4][8];
    #pragma unroll
    for (int q = 0; q < 8; ++q) {
      acc[0][q] = bias0.x; acc[1][q] = bias0.y;
      acc[2][q] = bias0.z; acc[3][q] = bias0.w;
    }
    MM_STEP(WT_IH0, &sinp[0][0], 16, 16)                 // x @ w_ih0^T (padded to 16)
    MM_STEP(WT_HH0, &sh0[cur][0][0], 128, 128)           // h0 @ w_hh0^T
    #pragma unroll
    for (int q = 0; q < 8; ++q) {
      float ig = sigmoid_f(acc[0][q]);
      float fg = sigmoid_f(acc[1][q]);
      float gg = tanh_f(acc[2][q]);
      float og = sigmoid_f(acc[3][q]);
      float c  = fg * c0r[q] + ig * gg;
      c0r[q]   = c;
      sh0[nxt][bl + q][j] = og * tanh_f(c);
    }
    __syncthreads();

    // ---------------- layer 1 ----------------
    #pragma unroll
    for (int q = 0; q < 8; ++q) {
      acc[0][q] = bias1.x; acc[1][q] = bias1.y;
      acc[2][q] = bias1.z; acc[3][q] = bias1.w;
    }
    MM_STEP(WT_IH1, &sh0[nxt][0][0], 128, 128)           // h0_new @ w_ih1^T
    MM_STEP(WT_HH1, &sh1[cur][0][0], 128, 128)           // h1 @ w_hh1^T
    #pragma unroll
    for (int q = 0; q < 8; ++q) {
      float ig = sigmoid_f(acc[0][q]);
      float fg = sigmoid_f(acc[1][q]);
      float gg = tanh_f(acc[2][q]);
      float og = sigmoid_f(acc[3][q]);
      float c  = fg * c1r[q] + ig * gg;
      c1r[q]   = c;
      sh1[nxt][bl + q][j] = og * tanh_f(c);
    }
    __syncthreads();

    // ---------------- epilogue ----------------
    if (s < SEQ - 1) {
      // stage x[:, s+1, :] for the next encoder step
      if (tid < BT * NIN) {
        int b = tid / NIN, i = tid - b * NIN;
        sinp[b][i] = x[(bbase + b) * SEQ * NIN + (s + 1) * NIN + i];
      }
    } else if (s >= SEQ) {
      // decoder: pred = h1 @ fc_w^T + fc_b ; emit and feed back into inp[:,0:2]
      const int d = s - SEQ;
      if (tid < 64) {
        int b = tid >> 1, o = tid & 1;
        const float* wrow = fcw + o * 128;
        float p = fcb[o];
        for (int m = 0; m < 128; ++m) p = fmaf(sh1[nxt][b][m], wrow[m], p);
        out[(bbase + b) * (FUT * 2) + d * 2 + o] = p;
        sinp[b][o] = p;
      }
    }
    // s == SEQ-1: nothing — inp keeps x[:, S-1, :] as the first decoder input
    __syncthreads();

    cur = nxt;
  }
}

extern "C" void kernel_launch(void* const* d_in, const int* in_sizes, int n_in,
                              void* d_out, int out_size, void* d_ws, size_t ws_size,
                              hipStream_t stream)
{
  (void)in_sizes; (void)n_in; (void)out_size; (void)ws_size;
  const float* x     = (const float*)d_in[0];
  const float* w_ih0 = (const float*)d_in[1];
  const float* w_hh0 = (const float*)d_in[2];
  const float* b_ih0 = (const float*)d_in[3];
  const float* b_hh0 = (const float*)d_in[4];
  const float* w_ih1 = (const float*)d_in[5];
  const float* w_hh1 = (const float*)d_in[6];
  const float* b_ih1 = (const float*)d_in[7];
  const float* b_hh1 = (const float*)d_in[8];
  const float* fcw   = (const float*)d_in[9];
  const float* fcb   = (const float*)d_in[10];
  float* out = (float*)d_out;
  float* ws  = (float*)d_ws;

  prep_kernel<<<(205824 + 255) / 256, 256, 0, stream>>>(
      w_ih0, w_hh0, b_ih0, b_hh0, w_ih1, w_hh1, b_ih1, b_hh1, ws);
  lstm_kernel<<<8192 / BT, 512, 0, stream>>>(x, ws, fcw, fcb, out);
}

// Round 2
// 1493.986 us; speedup vs baseline: 26.5369x; 26.5369x over previous
//
#include <hip/hip_runtime.h>

// R2: persistent-weight MFMA LSTM.
// 2-layer LSTM (H=128) encoder S=100 + autoregressive decoder F=30, B=8192.
// Key change vs R1: recurrent weights live in VGPRs as fp16 MFMA B-fragments
// (loaded once per block), killing the 26TB/launch weight re-read that left
// VALUBusy at 17.7%. Batch tile M=16 per block (512 blocks, 2 rounds on 256 CUs),
// 8 waves x N-slice 64. h/x tiles + gate matrix round-trip LDS.
// fp16 (2^-11 rounding) keeps 130-step recurrence error ~5e-4 < 1.98e-3 thr.

typedef _Float16 half_t;
typedef _Float16 half8 __attribute__((ext_vector_type(8)));
typedef float f32x4 __attribute__((ext_vector_type(4)));

#define SEQ 100
#define FUT 30
#define TOT (SEQ + FUT)
#define NIN 15
#define MB  16      // batch rows per block
#define GS  516     // gates LDS stride (floats): 516 % 8 == 4 -> quads split banks, 16B aligned
#define HS  136     // h LDS stride (halfwords): 128+8, keeps 16B align, 2-way banks max
#define XS  24      // x LDS stride (halfwords)

__device__ __forceinline__ float sigm(float v) { return 1.0f / (1.0f + __expf(-v)); }
__device__ __forceinline__ float tanh_(float v) {
  float a = fabsf(v);
  float e = __expf(-2.0f * a);
  float t = (1.0f - e) / (1.0f + e);
  return (v < 0.0f) ? -t : t;
}

// ---- prep: repack weights to fp16 [n'][k] with n' = 4*j + gate, k row-major ----
// ws halfword layout:
//   [0,      65536)  WH0[n*128+k]
//   [65536, 131072)  WI1
//   [131072,196608)  WH1
//   [196608,212992)  WI0[n*32+k]  (k>=15 zero)
//   floats at halfword 212992: BV0[512], BV1[512]  (b_ih + b_hh, n' order)
__global__ void prep_kernel(const float* __restrict__ w_ih0, const float* __restrict__ w_hh0,
                            const float* __restrict__ b_ih0, const float* __restrict__ b_hh0,
                            const float* __restrict__ w_ih1, const float* __restrict__ w_hh1,
                            const float* __restrict__ b_ih1, const float* __restrict__ b_hh1,
                            half_t* __restrict__ wsh)
{
  int idx = blockIdx.x * 256 + threadIdx.x;
  if (idx < 196608) {
    int seg = idx >> 16;
    int r   = idx & 65535;
    int n   = r >> 7, k = r & 127;
    int row = (n & 3) * 128 + (n >> 2);          // PyTorch gate-major row
    const float* src = (seg == 0) ? w_hh0 : ((seg == 1) ? w_ih1 : w_hh1);
    wsh[idx] = (half_t)src[row * 128 + k];
  } else if (idx < 212992) {
    int r   = idx - 196608;
    int n   = r >> 5, k = r & 31;
    int row = (n & 3) * 128 + (n >> 2);
    wsh[idx] = (half_t)((k < NIN) ? w_ih0[row * NIN + k] : 0.0f);
  } else if (idx < 214016) {
    int r     = idx - 212992;
    float* bv = (float*)(wsh + 212992);
    int which = r >> 9, n = r & 511;
    int row   = (n & 3) * 128 + (n >> 2);
    bv[r] = (which == 0) ? (b_ih0[row] + b_hh0[row]) : (b_ih1[row] + b_hh1[row]);
  }
}

__global__ __launch_bounds__(512, 2)
void lstm_kernel(const float* __restrict__ x,
                 const half_t* __restrict__ wsh,
                 const float* __restrict__ fcw,
                 const float* __restrict__ fcb,
                 float* __restrict__ out)
{
  __shared__ __align__(16) float  gates[MB * GS];   // 33,024 B
  __shared__ __align__(16) half_t sh0[MB * HS];     // 4,352 B
  __shared__ __align__(16) half_t sh1[MB * HS];     // 4,352 B
  __shared__ __align__(16) half_t sxin[MB * XS];    // 768 B
  __shared__ __align__(16) float  sfc[256];         // fc_w staged

  const half_t* WH0 = wsh;
  const half_t* WI1 = wsh + 65536;
  const half_t* WH1 = wsh + 131072;
  const half_t* WI0 = wsh + 196608;
  const float*  BV  = (const float*)(wsh + 212992);

  const int tid   = threadIdx.x;
  const int wave  = tid >> 6;
  const int lane  = tid & 63;
  const int l16   = lane & 15;     // MFMA col (B) / row m (A/C)
  const int quad  = lane >> 4;     // MFMA k-quad / C row group
  const int nb    = wave * 64;     // this wave's N-slice base
  const int bbase = blockIdx.x * MB;

  // ---- persistent B-fragments (weights) ----
  half8 wh0[4][4], wi1[4][4], wh1[4][4];  // [kt][nt] : 192 VGPRs
  half8 wx[4];                            // WI0 [nt]  : 16 VGPRs
  #pragma unroll
  for (int kt = 0; kt < 4; ++kt) {
    #pragma unroll
    for (int nt = 0; nt < 4; ++nt) {
      int n = nb + nt * 16 + l16;
      int k = kt * 32 + quad * 8;
      wh0[kt][nt] = *(const half8*)&WH0[n * 128 + k];
      wi1[kt][nt] = *(const half8*)&WI1[n * 128 + k];
      wh1[kt][nt] = *(const half8*)&WH1[n * 128 + k];
    }
  }
  #pragma unroll
  for (int nt = 0; nt < 4; ++nt)
    wx[nt] = *(const half8*)&WI0[(nb + nt * 16 + l16) * 32 + quad * 8];

  // ---- activation-phase thread mapping ----
  const int aj  = tid & 127;   // hidden unit owned in act phase
  const int abq = tid >> 7;    // batch quarter (wave-uniform)
  f32x4 bias0 = *(const f32x4*)&BV[aj * 4];
  f32x4 bias1 = *(const f32x4*)&BV[512 + aj * 4];
  float c0[4] = {0.f, 0.f, 0.f, 0.f};
  float c1[4] = {0.f, 0.f, 0.f, 0.f};

  // ---- LDS init ----
  for (int i = tid; i < MB * HS; i += 512) { sh0[i] = (half_t)0; sh1[i] = (half_t)0; }
  for (int i = tid; i < MB * XS; i += 512) sxin[i] = (half_t)0;
  if (tid < 256) sfc[tid] = fcw[tid];
  __syncthreads();
  if (tid < MB * NIN) {
    int b = tid / NIN, ii = tid - b * NIN;
    sxin[b * XS + ii] = (half_t)x[(size_t)(bbase + b) * SEQ * NIN + ii];
  }
  __syncthreads();

  const f32x4 zero4 = {0.f, 0.f, 0.f, 0.f};

  for (int s = 0; s < TOT; ++s) {
    // prefetch next encoder frame early (hide global latency across phases)
    float xr = 0.f; int pb = 0, pi = 0;
    if (s < SEQ - 1 && tid < MB * NIN) {
      pb = tid / NIN; pi = tid - pb * NIN;
      xr = x[(size_t)(bbase + pb) * SEQ * NIN + (s + 1) * NIN + pi];
    }

    // ================= layer 0 MFMA =================
    {
      f32x4 acc[4];
      #pragma unroll
      for (int nt = 0; nt < 4; ++nt) acc[nt] = zero4;
      #pragma unroll
      for (int kt = 0; kt < 4; ++kt) {
        half8 ah = *(const half8*)&sh0[l16 * HS + kt * 32 + quad * 8];
        #pragma unroll
        for (int nt = 0; nt < 4; ++nt)
          acc[nt] = __builtin_amdgcn_mfma_f32_16x16x32_f16(ah, wh0[kt][nt], acc[nt], 0, 0, 0);
      }
      half8 ax = *(const half8*)&sxin[l16 * XS + quad * 8];
      #pragma unroll
      for (int nt = 0; nt < 4; ++nt)
        acc[nt] = __builtin_amdgcn_mfma_f32_16x16x32_f16(ax, wx[nt], acc[nt], 0, 0, 0);
      #pragma unroll
      for (int nt = 0; nt < 4; ++nt)
        #pragma unroll
        for (int r = 0; r < 4; ++r)
          gates[(quad * 4 + r) * GS + nb + nt * 16 + l16] = acc[nt][r];
    }
    __syncthreads();  // B1: gates0 ready; h0 reads done

    // ================= act 0 =================
    #pragma unroll
    for (int i = 0; i < 4; ++i) {
      int b = abq * 4 + i;
      f32x4 q = *(const f32x4*)&gates[b * GS + aj * 4];
      float ig = sigm(q[0] + bias0[0]);
      float fg = sigm(q[1] + bias0[1]);
      float gc = tanh_(q[2] + bias0[2]);
      float og = sigm(q[3] + bias0[3]);
      float c  = fg * c0[i] + ig * gc;
      c0[i] = c;
      sh0[b * HS + aj] = (half_t)(og * tanh_(c));
    }
    __syncthreads();  // B2: h0_new ready; gates0 reads done

    // ================= layer 1 MFMA =================
    {
      f32x4 acc[4];
      #pragma unroll
      for (int nt = 0; nt < 4; ++nt) acc[nt] = zero4;
      #pragma unroll
      for (int kt = 0; kt < 4; ++kt) {
        half8 ah = *(const half8*)&sh0[l16 * HS + kt * 32 + quad * 8];
        #pragma unroll
        for (int nt = 0; nt < 4; ++nt)
          acc[nt] = __builtin_amdgcn_mfma_f32_16x16x32_f16(ah, wi1[kt][nt], acc[nt], 0, 0, 0);
      }
      #pragma unroll
      for (int kt = 0; kt < 4; ++kt) {
        half8 ah = *(const half8*)&sh1[l16 * HS + kt * 32 + quad * 8];
        #pragma unroll
        for (int nt = 0; nt < 4; ++nt)
          acc[nt] = __builtin_amdgcn_mfma_f32_16x16x32_f16(ah, wh1[kt][nt], acc[nt], 0, 0, 0);
      }
      #pragma unroll
      for (int nt = 0; nt < 4; ++nt)
        #pragma unroll
        for (int r = 0; r < 4; ++r)
          gates[(quad * 4 + r) * GS + nb + nt * 16 + l16] = acc[nt][r];
    }
    __syncthreads();  // B3: gates1 ready; h1 reads done

    // ================= act 1 =================
    #pragma unroll
    for (int i = 0; i < 4; ++i) {
      int b = abq * 4 + i;
      f32x4 q = *(const f32x4*)&gates[b * GS + aj * 4];
      float ig = sigm(q[0] + bias1[0]);
      float fg = sigm(q[1] + bias1[1]);
      float gc = tanh_(q[2] + bias1[2]);
      float og = sigm(q[3] + bias1[3]);
      float c  = fg * c1[i] + ig * gc;
      c1[i] = c;
      sh1[b * HS + aj] = (half_t)(og * tanh_(c));
    }
    __syncthreads();  // B4: h1_new ready; gates1 reads done

    // ================= FC (decoder) / x staging (encoder) =================
    if (s >= SEQ) {
      if (tid < 32) {
        int b = tid >> 1, o = tid & 1;
        float p = fcb[o];
        #pragma unroll
        for (int k8 = 0; k8 < 16; ++k8) {
          half8 hv = *(const half8*)&sh1[b * HS + k8 * 8];
          const float* wr = &sfc[o * 128 + k8 * 8];
          #pragma unroll
          for (int u = 0; u < 8; ++u) p = fmaf((float)hv[u], wr[u], p);
        }
        out[(size_t)(bbase + b) * (FUT * 2) + (s - SEQ) * 2 + o] = p;
        sxin[b * XS + o] = (half_t)p;   // feed back into input features 0:2
      }
    } else if (s < SEQ - 1) {
      if (tid < MB * NIN) sxin[pb * XS + pi] = (half_t)xr;
    }
    // s == SEQ-1: keep frame 99 as first decoder input
    __syncthreads();  // B5: sxin ready for next layer-0 MFMA
  }
}

extern "C" void kernel_launch(void* const* d_in, const int* in_sizes, int n_in,
                              void* d_out, int out_size, void* d_ws, size_t ws_size,
                              hipStream_t stream)
{
  (void)in_sizes; (void)n_in; (void)out_size; (void)ws_size;
  const float* x     = (const float*)d_in[0];
  const float* w_ih0 = (const float*)d_in[1];
  const float* w_hh0 = (const float*)d_in[2];
  const float* b_ih0 = (const float*)d_in[3];
  const float* b_hh0 = (const float*)d_in[4];
  const float* w_ih1 = (const float*)d_in[5];
  const float* w_hh1 = (const float*)d_in[6];
  const float* b_ih1 = (const float*)d_in[7];
  const float* b_hh1 = (const float*)d_in[8];
  const float* fcw   = (const float*)d_in[9];
  const float* fcb   = (const float*)d_in[10];
  float*  out = (float*)d_out;
  half_t* wsh = (half_t*)d_ws;

  prep_kernel<<<(214016 + 255) / 256, 256, 0, stream>>>(
      w_ih0, w_hh0, b_ih0, b_hh0, w_ih1, w_hh1, b_ih1, b_hh1, wsh);
  lstm_kernel<<<8192 / MB, 512, 0, stream>>>(x, wsh, fcw, fcb, out);
}

// Round 3
// 1165.132 us; speedup vs baseline: 34.0268x; 1.2822x over previous
//
#include <hip/hip_runtime.h>

// R3: register-direct activations.
// vs R2: (1) gate columns reordered (col = 64*wave + 16*gate + unit) so each
// wave's MFMA accumulators hold all 4 gates of its own units in-lane -> act
// reads acc registers directly; 33KB gates LDS array + its 8-way conflicts +
// 2 barriers eliminated. (2) IEEE divides -> v_rcp_f32, __expf -> v_exp_f32,
// log2e scales pre-folded into fp16 weights/biases. (3) bias folded into
// MFMA acc init. Barriers 5 -> 2 per step (+1 decode). 1 block/CU (232 regs),
// 512 blocks = 2 rounds.

typedef _Float16 half_t;
typedef _Float16 half8 __attribute__((ext_vector_type(8)));
typedef float f32x4 __attribute__((ext_vector_type(4)));

#define SEQ 100
#define FUT 30
#define TOT (SEQ + FUT)
#define NIN 15
#define MB  16
#define HS  136     // h LDS row stride (halfwords)
#define XS  24      // x LDS row stride (halfwords)
#define L2E 1.44269504f

// v pre-scaled by -log2(e): sigmoid(x) = 1/(1+2^(-log2e*x))
__device__ __forceinline__ float sigm_pre(float v) {
  return __builtin_amdgcn_rcpf(1.0f + __builtin_amdgcn_exp2f(v));
}
// v pre-scaled by 2*log2(e): tanh(x) = 1 - 2/(2^(2*log2e*x)+1)
__device__ __forceinline__ float tanh_pre(float v) {
  return fmaf(-2.0f, __builtin_amdgcn_rcpf(1.0f + __builtin_amdgcn_exp2f(v)), 1.0f);
}

// ---- prep: repack weights to fp16 [n'][k], n' = 64*(j/16) + 16*g + (j%16),
// with per-gate scale folded in: g in {i,f,o} -> -log2e ; g==2 (cell) -> +2*log2e.
// ws halfword layout:
//   [0,      65536)  WH0[n*128+k]
//   [65536, 131072)  WI1
//   [131072,196608)  WH1
//   [196608,212992)  WI0[n*32+k]  (k>=15 zero)
//   floats at halfword 212992: BV[1024] = scaled (b_ih+b_hh), layer0 then layer1
__global__ void prep_kernel(const float* __restrict__ w_ih0, const float* __restrict__ w_hh0,
                            const float* __restrict__ b_ih0, const float* __restrict__ b_hh0,
                            const float* __restrict__ w_ih1, const float* __restrict__ w_hh1,
                            const float* __restrict__ b_ih1, const float* __restrict__ b_hh1,
                            half_t* __restrict__ wsh)
{
  int idx = blockIdx.x * 256 + threadIdx.x;
  if (idx < 196608) {
    int seg = idx >> 16;
    int r   = idx & 65535;
    int n   = r >> 7, k = r & 127;
    int g   = (n >> 4) & 3;
    int row = g * 128 + ((n >> 6) << 4) + (n & 15);
    float sc = (g == 2) ? (2.0f * L2E) : (-L2E);
    const float* src = (seg == 0) ? w_hh0 : ((seg == 1) ? w_ih1 : w_hh1);
    wsh[idx] = (half_t)(src[row * 128 + k] * sc);
  } else if (idx < 212992) {
    int r   = idx - 196608;
    int n   = r >> 5, k = r & 31;
    int g   = (n >> 4) & 3;
    int row = g * 128 + ((n >> 6) << 4) + (n & 15);
    float sc = (g == 2) ? (2.0f * L2E) : (-L2E);
    wsh[idx] = (half_t)((k < NIN) ? (w_ih0[row * NIN + k] * sc) : 0.0f);
  } else if (idx < 214016) {
    int r     = idx - 212992;
    float* bv = (float*)(wsh + 212992);
    int which = r >> 9, n = r & 511;
    int g     = (n >> 4) & 3;
    int row   = g * 128 + ((n >> 6) << 4) + (n & 15);
    float sc  = (g == 2) ? (2.0f * L2E) : (-L2E);
    bv[r] = ((which == 0) ? (b_ih0[row] + b_hh0[row]) : (b_ih1[row] + b_hh1[row])) * sc;
  }
}

#define MFMA(A, B, C) __builtin_amdgcn_mfma_f32_16x16x32_f16((A), (B), (C), 0, 0, 0)

__global__ __launch_bounds__(512, 2)
void lstm_kernel(const float* __restrict__ x,
                 const half_t* __restrict__ wsh,
                 const float* __restrict__ fcw,
                 const float* __restrict__ fcb,
                 float* __restrict__ out)
{
  __shared__ __align__(16) half_t sh0[2][MB * HS];
  __shared__ __align__(16) half_t sh1[2][MB * HS];
  __shared__ __align__(16) half_t sxin[MB * XS + 32];  // +pad: quad-3 A-reads overrun x0
  __shared__ __align__(16) float  sfc[256];

  const half_t* WH0 = wsh;
  const half_t* WI1 = wsh + 65536;
  const half_t* WH1 = wsh + 131072;
  const half_t* WI0 = wsh + 196608;
  const float*  BV  = (const float*)(wsh + 212992);

  const int tid   = threadIdx.x;
  const int wave  = tid >> 6;
  const int lane  = tid & 63;
  const int l16   = lane & 15;     // unit-within-wave (B cols / C cols) ; batch row for A
  const int quad  = lane >> 4;     // k-quad for A/B ; C row group
  const int nb    = wave * 64;     // wave's gate-col slice base
  const int bbase = blockIdx.x * MB;

  // ---- persistent B-fragments (weights), n = nb + 16*g + l16 ----
  half8 wh0[4][4], wi1[4][4], wh1[4][4];  // [kt][g]
  half8 wx[4];                            // [g]
  #pragma unroll
  for (int kt = 0; kt < 4; ++kt) {
    #pragma unroll
    for (int g = 0; g < 4; ++g) {
      int n = nb + g * 16 + l16;
      int k = kt * 32 + quad * 8;
      wh0[kt][g] = *(const half8*)&WH0[n * 128 + k];
      wi1[kt][g] = *(const half8*)&WI1[n * 128 + k];
      wh1[kt][g] = *(const half8*)&WH1[n * 128 + k];
    }
  }
  #pragma unroll
  for (int g = 0; g < 4; ++g)
    wx[g] = *(const half8*)&WI0[(nb + g * 16 + l16) * 32 + quad * 8];

  // biases (scaled), per owned unit: b[g] = BV[nb + 16g + l16]
  float b0[4], b1[4];
  #pragma unroll
  for (int g = 0; g < 4; ++g) {
    b0[g] = BV[nb + g * 16 + l16];
    b1[g] = BV[512 + nb + g * 16 + l16];
  }

  // cell state: unit = 16*wave + l16, batches quad*4 + r
  float c0[4] = {0.f, 0.f, 0.f, 0.f};
  float c1[4] = {0.f, 0.f, 0.f, 0.f};

  // ---- LDS init ----
  for (int i = tid; i < MB * HS; i += 512) {
    sh0[0][i] = (half_t)0; sh0[1][i] = (half_t)0;
    sh1[0][i] = (half_t)0; sh1[1][i] = (half_t)0;
  }
  for (int i = tid; i < MB * XS + 32; i += 512) sxin[i] = (half_t)0;
  if (tid < 256) sfc[tid] = fcw[tid];
  __syncthreads();
  if (tid < MB * NIN) {
    int b = tid / NIN, ii = tid - b * NIN;
    sxin[b * XS + ii] = (half_t)x[(size_t)(bbase + b) * SEQ * NIN + ii];
  }
  float fcb_o = (tid < 32) ? fcb[tid & 1] : 0.f;
  __syncthreads();

  int cur = 0;
  for (int s = 0; s < TOT; ++s) {
    const int nxt = cur ^ 1;

    // prefetch next encoder frame (consumed just before B2)
    float xr = 0.f; int pb = 0, pi = 0;
    const bool havex = (s < SEQ - 1) && (tid < MB * NIN);
    if (havex) {
      pb = tid / NIN; pi = tid - pb * NIN;
      xr = x[(size_t)(bbase + pb) * SEQ * NIN + (s + 1) * NIN + pi];
    }

    // ================= P0: layer 0 MFMA + act0 (register-direct) =================
    {
      f32x4 acc[4];
      #pragma unroll
      for (int g = 0; g < 4; ++g) acc[g] = (f32x4){b0[g], b0[g], b0[g], b0[g]};
      #pragma unroll
      for (int kt = 0; kt < 4; ++kt) {
        half8 ah = *(const half8*)&sh0[cur][l16 * HS + kt * 32 + quad * 8];
        #pragma unroll
        for (int g = 0; g < 4; ++g) acc[g] = MFMA(ah, wh0[kt][g], acc[g]);
      }
      half8 ax = *(const half8*)&sxin[l16 * XS + quad * 8];
      #pragma unroll
      for (int g = 0; g < 4; ++g) acc[g] = MFMA(ax, wx[g], acc[g]);

      #pragma unroll
      for (int r = 0; r < 4; ++r) {
        float sI = sigm_pre(acc[0][r]);
        float sF = sigm_pre(acc[1][r]);
        float tG = tanh_pre(acc[2][r]);
        float sO = sigm_pre(acc[3][r]);
        float c  = fmaf(sF, c0[r], sI * tG);
        c0[r] = c;
        float tC = tanh_pre(2.0f * L2E * c);
        sh0[nxt][(quad * 4 + r) * HS + wave * 16 + l16] = (half_t)(sO * tC);
      }
    }
    __syncthreads();  // B1: h0_new visible

    // ================= P1: layer 1 MFMA + act1 + x staging =================
    {
      f32x4 acc[4];
      #pragma unroll
      for (int g = 0; g < 4; ++g) acc[g] = (f32x4){b1[g], b1[g], b1[g], b1[g]};
      #pragma unroll
      for (int kt = 0; kt < 4; ++kt) {
        half8 ah = *(const half8*)&sh0[nxt][l16 * HS + kt * 32 + quad * 8];
        #pragma unroll
        for (int g = 0; g < 4; ++g) acc[g] = MFMA(ah, wi1[kt][g], acc[g]);
      }
      #pragma unroll
      for (int kt = 0; kt < 4; ++kt) {
        half8 ah = *(const half8*)&sh1[cur][l16 * HS + kt * 32 + quad * 8];
        #pragma unroll
        for (int g = 0; g < 4; ++g) acc[g] = MFMA(ah, wh1[kt][g], acc[g]);
      }

      if (havex) sxin[pb * XS + pi] = (half_t)xr;  // safe: sxin readers done pre-B1

      #pragma unroll
      for (int r = 0; r < 4; ++r) {
        float sI = sigm_pre(acc[0][r]);
        float sF = sigm_pre(acc[1][r]);
        float tG = tanh_pre(acc[2][r]);
        float sO = sigm_pre(acc[3][r]);
        float c  = fmaf(sF, c1[r], sI * tG);
        c1[r] = c;
        float tC = tanh_pre(2.0f * L2E * c);
        sh1[nxt][(quad * 4 + r) * HS + wave * 16 + l16] = (half_t)(sO * tC);
      }
    }
    __syncthreads();  // B2: h1_new + sxin visible

    // ================= decoder FC =================
    if (s >= SEQ) {
      if (tid < 32) {
        int b = tid >> 1, o = tid & 1;
        float p = fcb_o;
        #pragma unroll
        for (int k8 = 0; k8 < 16; ++k8) {
          half8 hv = *(const half8*)&sh1[nxt][b * HS + k8 * 8];
          const float* wr = &sfc[o * 128 + k8 * 8];
          #pragma unroll
          for (int u = 0; u < 8; ++u) p = fmaf((float)hv[u], wr[u], p);
        }
        out[(size_t)(bbase + b) * (FUT * 2) + (s - SEQ) * 2 + o] = p;
        sxin[b * XS + o] = (half_t)p;   // feed back into input features 0:2
      }
      __syncthreads();  // B3 (decode only): sxin feedback visible
    }

    cur = nxt;
  }
}

extern "C" void kernel_launch(void* const* d_in, const int* in_sizes, int n_in,
                              void* d_out, int out_size, void* d_ws, size_t ws_size,
                              hipStream_t stream)
{
  (void)in_sizes; (void)n_in; (void)out_size; (void)ws_size;
  const float* x     = (const float*)d_in[0];
  const float* w_ih0 = (const float*)d_in[1];
  const float* w_hh0 = (const float*)d_in[2];
  const float* b_ih0 = (const float*)d_in[3];
  const float* b_hh0 = (const float*)d_in[4];
  const float* w_ih1 = (const float*)d_in[5];
  const float* w_hh1 = (const float*)d_in[6];
  const float* b_ih1 = (const float*)d_in[7];
  const float* b_hh1 = (const float*)d_in[8];
  const float* fcw   = (const float*)d_in[9];
  const float* fcb   = (const float*)d_in[10];
  float*  out = (float*)d_out;
  half_t* wsh = (half_t*)d_ws;

  prep_kernel<<<(214016 + 255) / 256, 256, 0, stream>>>(
      w_ih0, w_hh0, b_ih0, b_hh0, w_ih1, w_hh1, b_ih1, b_hh1, wsh);
  lstm_kernel<<<8192 / MB, 512, 0, stream>>>(x, wsh, fcw, fcb, out);
}

// Round 4
// 731.324 us; speedup vs baseline: 54.2109x; 1.5932x over previous
//
#include <hip/hip_runtime.h>

// R4: spill-free persistent-weight MFMA LSTM.
// vs R3 (which spilled: live regs ~264 > 256 cap of an 8-wave block; WRITE_SIZE
// 63.5MB of scratch traffic): (1) W_ih0 + biases moved to LDS, x-weight frags
// loaded one-at-a-time -> peak live ~232 regs, no spill. (2) h-tiles XOR-swizzled
// (stride 128 halfs, chunk ^ (row&7)): R3's HS=136 put rows on 8 bank-groups ->
// 8-way conflicts on every ds_read_b128; now 2-way (free). (3) whole x sequence
// staged to LDS once (51KB) -> zero global ops in the recurrence loop -> no
// vmcnt(0) drains at barriers. (4) encoder needs only ONE barrier per step
// (double-buffered sh0/sh1: every producer->consumer pair spans the next B1).

typedef _Float16 half_t;
typedef _Float16 half8 __attribute__((ext_vector_type(8)));
typedef float f32x4 __attribute__((ext_vector_type(4)));

#define SEQ 100
#define FUT 30
#define TOT (SEQ + FUT)
#define NIN 15
#define MB  16
#define L2E 1.44269504f

__device__ __forceinline__ float sigm_pre(float v) {   // v pre-scaled by -log2e
  return __builtin_amdgcn_rcpf(1.0f + __builtin_amdgcn_exp2f(v));
}
__device__ __forceinline__ float tanh_pre(float v) {   // v pre-scaled by +2log2e
  return fmaf(-2.0f, __builtin_amdgcn_rcpf(1.0f + __builtin_amdgcn_exp2f(v)), 1.0f);
}

#define MFMA(A, B, C) __builtin_amdgcn_mfma_f32_16x16x32_f16((A), (B), (C), 0, 0, 0)

// ---- prep: fp16 repack, gate scales folded (i,f,o: -log2e ; cell g: +2log2e).
// n' = 64*wave + 16*gate + unit%16, unit j = 16*wave + (n&15), row = g*128 + j.
// ws halfword layout:
//   [0,      65536)  WH0[n*128+k]
//   [65536, 131072)  WI1[n*128+k]
//   [131072,196608)  WH1[n*128+k]
//   [196608,204800)  WX [n*16+k]   (k>=15 zero)
//   [204800,206848)  BV: 1024 f32 = scaled (b_ih+b_hh), layer0 then layer1
__global__ void prep_kernel(const float* __restrict__ w_ih0, const float* __restrict__ w_hh0,
                            const float* __restrict__ b_ih0, const float* __restrict__ b_hh0,
                            const float* __restrict__ w_ih1, const float* __restrict__ w_hh1,
                            const float* __restrict__ b_ih1, const float* __restrict__ b_hh1,
                            half_t* __restrict__ wsh)
{
  int idx = blockIdx.x * 256 + threadIdx.x;
  if (idx < 196608) {
    int seg = idx >> 16;
    int r   = idx & 65535;
    int n   = r >> 7, k = r & 127;
    int g   = (n >> 4) & 3;
    int row = g * 128 + ((n >> 6) << 4) + (n & 15);
    float sc = (g == 2) ? (2.0f * L2E) : (-L2E);
    const float* src = (seg == 0) ? w_hh0 : ((seg == 1) ? w_ih1 : w_hh1);
    wsh[idx] = (half_t)(src[row * 128 + k] * sc);
  } else if (idx < 204800) {
    int r   = idx - 196608;
    int n   = r >> 4, k = r & 15;
    int g   = (n >> 4) & 3;
    int row = g * 128 + ((n >> 6) << 4) + (n & 15);
    float sc = (g == 2) ? (2.0f * L2E) : (-L2E);
    wsh[idx] = (half_t)((k < NIN) ? (w_ih0[row * NIN + k] * sc) : 0.0f);
  } else if (idx < 205824) {
    int r     = idx - 204800;
    float* bv = (float*)(wsh + 204800);
    int which = r >> 9, n = r & 511;
    int g     = (n >> 4) & 3;
    int row   = g * 128 + ((n >> 6) << 4) + (n & 15);
    float sc  = (g == 2) ? (2.0f * L2E) : (-L2E);
    bv[r] = ((which == 0) ? (b_ih0[row] + b_hh0[row]) : (b_ih1[row] + b_hh1[row])) * sc;
  }
}

__global__ __launch_bounds__(512, 2)
void lstm_kernel(const float* __restrict__ x,
                 const half_t* __restrict__ wsh,
                 const float* __restrict__ fcw,
                 const float* __restrict__ fcb,
                 float* __restrict__ out)
{
  // XOR-swizzled h tiles: element (row r, col k) lives at
  //   r*128 + (((k>>3) ^ (r&7))<<3) + (k&7)   [halfwords]
  __shared__ __align__(16) half_t sx[SEQ * MB * 16];  // [s][b][16] 51,200 B
  __shared__ __align__(16) half_t sh0[2][MB * 128];   // 8,192 B
  __shared__ __align__(16) half_t sh1[2][MB * 128];   // 8,192 B
  __shared__ __align__(16) half_t swx[512 * 16];      // 16,384 B
  __shared__ __align__(16) half_t sdec[MB * 16];      // decoder input, 512 B
  __shared__ __align__(16) float  sbias[1024];        // 4,096 B
  __shared__ __align__(16) float  sfc[258];           // fc_w + fc_b

  const half_t* WH0 = wsh;
  const half_t* WI1 = wsh + 65536;
  const half_t* WH1 = wsh + 131072;
  const half_t* WX  = wsh + 196608;
  const float*  BV  = (const float*)(wsh + 204800);

  const int tid   = threadIdx.x;
  const int wave  = tid >> 6;
  const int lane  = tid & 63;
  const int l16   = lane & 15;
  const int quad  = lane >> 4;
  const int nb    = wave * 64;
  const int bbase = blockIdx.x * MB;

  // ---- persistent B-fragments: recurrent weights only (192 VGPRs) ----
  half8 wh0[4][4], wi1[4][4], wh1[4][4];  // [kt][g]
  #pragma unroll
  for (int kt = 0; kt < 4; ++kt) {
    #pragma unroll
    for (int g = 0; g < 4; ++g) {
      int n = nb + g * 16 + l16;
      int k = kt * 32 + quad * 8;
      wh0[kt][g] = *(const half8*)&WH0[n * 128 + k];
      wi1[kt][g] = *(const half8*)&WI1[n * 128 + k];
      wh1[kt][g] = *(const half8*)&WH1[n * 128 + k];
    }
  }

  // ---- one-time LDS staging ----
  for (int it = tid; it < MB * SEQ * NIN; it += 512) {
    int b = it / (SEQ * NIN); int r = it - b * (SEQ * NIN);
    int s = r / NIN;          int i = r - s * NIN;
    sx[(s * MB + b) * 16 + i] = (half_t)x[(size_t)(bbase + b) * (SEQ * NIN) + r];
  }
  for (int it = tid; it < SEQ * MB; it += 512) sx[it * 16 + 15] = (half_t)0;
  for (int it = tid; it < 8192; it += 512)     swx[it] = WX[it];
  for (int it = tid; it < 1024; it += 512)     sbias[it] = BV[it];
  if (tid < 256) sfc[tid] = fcw[tid];
  if (tid < 2)   sfc[256 + tid] = fcb[tid];
  if (tid < 256) {
    int b = tid >> 4, i = tid & 15;
    sdec[tid] = (i < NIN) ? (half_t)x[(size_t)(bbase + b) * (SEQ * NIN) + 99 * NIN + i]
                          : (half_t)0;
  }
  for (int it = tid; it < MB * 128; it += 512) {
    sh0[0][it] = (half_t)0; sh0[1][it] = (half_t)0;
    sh1[0][it] = (half_t)0; sh1[1][it] = (half_t)0;
  }
  __syncthreads();

  float c0[4] = {0.f, 0.f, 0.f, 0.f};
  float c1[4] = {0.f, 0.f, 0.f, 0.f};
  const half8 zero8 = {(half_t)0, (half_t)0, (half_t)0, (half_t)0,
                       (half_t)0, (half_t)0, (half_t)0, (half_t)0};

  int cur = 0;
  for (int s = 0; s < TOT; ++s) {
    const int nxt = cur ^ 1;
    const half_t* xsrc = (s < SEQ) ? &sx[s * MB * 16] : sdec;

    // ================= P0: layer 0 =================
    {
      f32x4 acc[4];
      #pragma unroll
      for (int g = 0; g < 4; ++g) {
        float b = sbias[nb + g * 16 + l16];
        acc[g] = (f32x4){b, b, b, b};
      }
      #pragma unroll
      for (int kt = 0; kt < 4; ++kt) {
        int c = kt * 4 + quad;
        half8 ah = *(const half8*)&sh0[cur][l16 * 128 + ((c ^ (l16 & 7)) << 3)];
        #pragma unroll
        for (int g = 0; g < 4; ++g) acc[g] = MFMA(ah, wh0[kt][g], acc[g]);
      }
      // x contribution (K=32, only quads 0-1 carry data; weights zero beyond k=15)
      half8 ax = zero8;
      if (quad < 2) ax = *(const half8*)&xsrc[l16 * 16 + quad * 8];
      #pragma unroll
      for (int g = 0; g < 4; ++g) {
        half8 bx = zero8;
        if (quad < 2) bx = *(const half8*)&swx[(nb + g * 16 + l16) * 16 + quad * 8];
        acc[g] = MFMA(ax, bx, acc[g]);
      }
      // act0 -> sh0[nxt]
      #pragma unroll
      for (int r = 0; r < 4; ++r) {
        int m = quad * 4 + r;
        float sI = sigm_pre(acc[0][r]);
        float sF = sigm_pre(acc[1][r]);
        float tG = tanh_pre(acc[2][r]);
        float sO = sigm_pre(acc[3][r]);
        float c  = fmaf(sF, c0[r], sI * tG);
        c0[r] = c;
        float h = sO * tanh_pre(2.0f * L2E * c);
        int chunk = wave * 2 + (l16 >> 3);
        sh0[nxt][m * 128 + ((chunk ^ (m & 7)) << 3) + (l16 & 7)] = (half_t)h;
      }
    }
    __syncthreads();  // B1 (the only encoder barrier)

    // ================= P1: layer 1 =================
    {
      f32x4 acc[4];
      #pragma unroll
      for (int g = 0; g < 4; ++g) {
        float b = sbias[512 + nb + g * 16 + l16];
        acc[g] = (f32x4){b, b, b, b};
      }
      #pragma unroll
      for (int kt = 0; kt < 4; ++kt) {
        int c = kt * 4 + quad;
        half8 ah = *(const half8*)&sh0[nxt][l16 * 128 + ((c ^ (l16 & 7)) << 3)];
        #pragma unroll
        for (int g = 0; g < 4; ++g) acc[g] = MFMA(ah, wi1[kt][g], acc[g]);
      }
      #pragma unroll
      for (int kt = 0; kt < 4; ++kt) {
        int c = kt * 4 + quad;
        half8 ah = *(const half8*)&sh1[cur][l16 * 128 + ((c ^ (l16 & 7)) << 3)];
        #pragma unroll
        for (int g = 0; g < 4; ++g) acc[g] = MFMA(ah, wh1[kt][g], acc[g]);
      }
      // act1 -> sh1[nxt]
      #pragma unroll
      for (int r = 0; r < 4; ++r) {
        int m = quad * 4 + r;
        float sI = sigm_pre(acc[0][r]);
        float sF = sigm_pre(acc[1][r]);
        float tG = tanh_pre(acc[2][r]);
        float sO = sigm_pre(acc[3][r]);
        float c  = fmaf(sF, c1[r], sI * tG);
        c1[r] = c;
        float h = sO * tanh_pre(2.0f * L2E * c);
        int chunk = wave * 2 + (l16 >> 3);
        sh1[nxt][m * 128 + ((chunk ^ (m & 7)) << 3) + (l16 & 7)] = (half_t)h;
      }
    }

    // ================= decoder: FC + feedback =================
    if (s >= SEQ) {
      __syncthreads();  // B2d: h1_new visible
      if (tid < 256) {
        // dot (b,o) split 8 ways over seg; lanes of a dot are contiguous in-wave
        int b   = wave * 4 + (lane >> 4);
        int o   = (lane >> 3) & 1;
        int seg = lane & 7;
        float p = 0.f;
        #pragma unroll
        for (int cc = 0; cc < 2; ++cc) {
          int c = seg * 2 + cc;
          half8 hv = *(const half8*)&sh1[nxt][b * 128 + ((c ^ (b & 7)) << 3)];
          f32x4 w0 = *(const f32x4*)&sfc[o * 128 + c * 8];
          f32x4 w1 = *(const f32x4*)&sfc[o * 128 + c * 8 + 4];
          #pragma unroll
          for (int u = 0; u < 4; ++u) p = fmaf((float)hv[u], w0[u], p);
          #pragma unroll
          for (int u = 0; u < 4; ++u) p = fmaf((float)hv[4 + u], w1[u], p);
        }
        p += __shfl_down(p, 4);
        p += __shfl_down(p, 2);
        p += __shfl_down(p, 1);
        if (seg == 0) {
          p += sfc[256 + o];
          out[(size_t)(bbase + b) * (FUT * 2) + (s - SEQ) * 2 + o] = p;
          sdec[b * 16 + o] = (half_t)p;   // feed back into features 0:2
        }
      }
      __syncthreads();  // B3d: sdec feedback visible
    }

    cur = nxt;
  }
}

extern "C" void kernel_launch(void* const* d_in, const int* in_sizes, int n_in,
                              void* d_out, int out_size, void* d_ws, size_t ws_size,
                              hipStream_t stream)
{
  (void)in_sizes; (void)n_in; (void)out_size; (void)ws_size;
  const float* x     = (const float*)d_in[0];
  const float* w_ih0 = (const float*)d_in[1];
  const float* w_hh0 = (const float*)d_in[2];
  const float* b_ih0 = (const float*)d_in[3];
  const float* b_hh0 = (const float*)d_in[4];
  const float* w_ih1 = (const float*)d_in[5];
  const float* w_hh1 = (const float*)d_in[6];
  const float* b_ih1 = (const float*)d_in[7];
  const float* b_hh1 = (const float*)d_in[8];
  const float* fcw   = (const float*)d_in[9];
  const float* fcb   = (const float*)d_in[10];
  float*  out = (float*)d_out;
  half_t* wsh = (half_t*)d_ws;

  prep_kernel<<<(205824 + 255) / 256, 256, 0, stream>>>(
      w_ih0, w_hh0, b_ih0, b_hh0, w_ih1, w_hh1, b_ih1, b_hh1, wsh);
  lstm_kernel<<<8192 / MB, 512, 0, stream>>>(x, wsh, fcw, fcb, out);
}